// Round 3
// baseline (108.008 us; speedup 1.0000x reference)
//
#include <hip/hip_runtime.h>

#define NMODELS 128
#define SZ_IN 256
#define SZ_OUT 256
#define MAXLIST 192   // P(cnt>192) ~ 0 (clamped for safety)
#define LDSK 264      // bf16 A-row stride: 2-way bank alias (free)
#define NT 512        // 8 waves
#define FRAGSTRIDE 520  // shorts per fragment slot: 512 data + 8 stagger
#define CPB 64        // cols per block (quarter split)
#define NTILES 4      // 16-col n-tiles per block
#define AROWS 64      // A rows staged per pass (covers max per-model cnt)

typedef __attribute__((ext_vector_type(4))) float f32x4;
typedef __attribute__((ext_vector_type(8))) short bf16x8;
typedef __attribute__((ext_vector_type(4))) short s16x4;

// fp32 -> bf16 RNE (bit pattern)
__device__ __forceinline__ short f2bf(float f) {
  union { float f; unsigned u; } v;
  v.f = f;
  const unsigned r = v.u + 0x7FFFu + ((v.u >> 16) & 1u);
  return (short)(r >> 16);
}

// R14 CALIBRATION (resubmit after GPU-acquisition timeout): kernel body
// identical to R13 (best, 84.7us single-launch). Launched 3x serially
// (idempotent: same out values rewritten; list membership deterministic).
// Purpose: dur_us_new - 84.7 = 2*K_warm resolves whether the kernel is
// ~40us (mystery resource) or ~6us (at HBM roofline, dur dominated by harness
// poison fills). Decision table in session journal.
__global__ __launch_bounds__(NT, 4) void linmulti_v13(
    const float* __restrict__ inp, const int* __restrict__ ids,
    const float* __restrict__ wlut, const float* __restrict__ blut,
    float* __restrict__ out, int B) {
  const int ch = blockIdx.x;   // 0..3 (64-col quarter)
  const int m = blockIdx.y;    // 0..127
  const int tid = threadIdx.x;
  const int lane = tid & 63;
  const int wv = tid >> 6;     // 0..7
  const int nt = wv & 3;       // n-tile (16 cols)
  const int par = wv >> 2;     // chunk parity: waves nt and nt+4 share B-frags
  const int q = lane >> 4;
  const int n16 = lane & 15;
  const int col = ch * CPB + nt * 16 + n16;

  __shared__ short Wfrag[32 * FRAGSTRIDE];  // 33,280 B: 8 kb x 4 ntiles
  __shared__ short As[AROWS * LDSK];        // 33,792 B: staged A rows
  __shared__ int list[MAXLIST];
  __shared__ int cnt0;

  if (tid == 0) cnt0 = 0;

  // ---- ids loads first (8 coalesced dwords/lane) ----
  int myid[8];
#pragma unroll
  for (int v = 0; v < 8; ++v) {
    const int b = v * NT + tid;
    myid[v] = (b < B) ? ids[b] : -1;
  }

  // ---- W slice, coalesced: 8 f32x4/thread, 256 B row segments ----
  const float* __restrict__ Wb = wlut + (size_t)m * (SZ_IN * SZ_OUT) + ch * CPB;
  f32x4 wraw[8];
#pragma unroll
  for (int v = 0; v < 8; ++v) {
    const int e4 = v * NT + tid;       // [0, 4096)
    const int r = e4 >> 4;             // k-row 0..255
    const int c4 = e4 & 15;            // f32x4 within the 64-col row
    wraw[v] = *(const f32x4*)(Wb + (size_t)r * SZ_OUT + c4 * 4);
  }

  __syncthreads();  // cnt0 = 0 visible

  // ---- member list: order-free atomic append (out rows are independent) ----
#pragma unroll
  for (int v = 0; v < 8; ++v) {
    if (myid[v] == m) {
      const int p = atomicAdd(&cnt0, 1);
      if (p < MAXLIST) list[p] = v * NT + tid;
    }
  }
  __syncthreads();
  const int cnt = (cnt0 < MAXLIST) ? cnt0 : MAXLIST;
  if (cnt == 0) return;  // uniform exit

  // ---- issue A-stage loads EARLY: latency hides under W scatter ----
  f32x4 araw[8];
#pragma unroll
  for (int v = 0; v < 8; ++v) {
    const int e4 = v * NT + tid;       // [0, 4096)
    const int s = e4 >> 6;             // staged row 0..63
    const int f4 = e4 & 63;            // f32x4 within 256-float row
    int p = s;
    if (p > cnt - 1) p = cnt - 1;      // pad rows clamp; stores guarded
    araw[v] = ((const f32x4*)(inp + (size_t)list[p] * SZ_IN))[f4];
  }

  // ---- cvt + scatter W into fragment-ordered LDS ----
  // element (k-row r, col c) -> frag f = (r>>5)*NTILES + (c>>4),
  //   slot = ((r>>3 & 3)*16 + (c&15))*8 + (r&7)
#pragma unroll
  for (int v = 0; v < 8; ++v) {
    const int e4 = v * NT + tid;
    const int r = e4 >> 4;
    const int c0 = (e4 & 15) * 4;
    const int kb = r >> 5;
    const int qq = (r >> 3) & 3;
    const int jj = r & 7;
#pragma unroll
    for (int e = 0; e < 4; ++e) {
      const int c = c0 + e;
      Wfrag[(kb * NTILES + (c >> 4)) * FRAGSTRIDE + ((qq * 16) + (c & 15)) * 8 + jj] =
          f2bf(wraw[v][e]);
    }
  }
  __syncthreads();

  // ---- extract this wave's 8 B-fragments (linear ds_read_b128) ----
  bf16x8 bfr[8];
#pragma unroll
  for (int kb = 0; kb < 8; ++kb)
    bfr[kb] = *(const bf16x8*)(Wfrag + (kb * NTILES + nt) * FRAGSTRIDE + lane * 8);

  const float bias_c = blut[m * SZ_OUT + col];

  // ---- pass loop (single pass for cnt <= 64; multi-pass for safety) ----
  for (int base = 0;;) {
    // write staged A (b64, conflict-free)
#pragma unroll
    for (int v = 0; v < 8; ++v) {
      const int e4 = v * NT + tid;
      const int s = e4 >> 6;
      const int f4 = e4 & 63;
      s16x4 h;
#pragma unroll
      for (int j = 0; j < 4; ++j) h[j] = f2bf(araw[v][j]);
      *(s16x4*)(As + s * LDSK + f4 * 4) = h;
    }
    __syncthreads();

    const int rows = ((cnt - base) < AROWS) ? (cnt - base) : AROWS;
    const int nchunk = (rows + 15) >> 4;
    // barrier-free compute: parity wave-sets split chunks
    for (int c = par; c < nchunk; c += 2) {
      f32x4 acc = (f32x4){0.f, 0.f, 0.f, 0.f};
#pragma unroll
      for (int kb = 0; kb < 8; ++kb) {
        const bf16x8 afr =
            *(const bf16x8*)(As + (c * 16 + n16) * LDSK + kb * 32 + q * 8);
        acc = __builtin_amdgcn_mfma_f32_16x16x32_bf16(afr, bfr[kb], acc, 0, 0, 0);
      }
#pragma unroll
      for (int r = 0; r < 4; ++r) {
        const int gr = base + c * 16 + q * 4 + r;
        if (gr < cnt)
          out[(size_t)list[gr] * SZ_OUT + col] = acc[r] + bias_c;
      }
    }

    base += AROWS;
    if (base >= cnt) break;
    __syncthreads();  // readers done before re-staging As (rare path)
#pragma unroll
    for (int v = 0; v < 8; ++v) {
      const int e4 = v * NT + tid;
      const int s = e4 >> 6;
      const int f4 = e4 & 63;
      int p = base + s;
      if (p > cnt - 1) p = cnt - 1;
      araw[v] = ((const f32x4*)(inp + (size_t)list[p] * SZ_IN))[f4];
    }
  }
}

extern "C" void kernel_launch(void* const* d_in, const int* in_sizes, int n_in,
                              void* d_out, int out_size, void* d_ws, size_t ws_size,
                              hipStream_t stream) {
  const float* inp = (const float*)d_in[0];
  const int* ids = (const int*)d_in[1];
  const float* wlut = (const float*)d_in[2];
  const float* blut = (const float*)d_in[3];
  float* out = (float*)d_out;
  const int B = in_sizes[1];

  // CALIBRATION: 3 identical serialized launches (idempotent).
  // dur_us - 84.7 = 2*K_warm resolves the kernel's true duration.
  linmulti_v13<<<dim3(4, NMODELS), NT, 0, stream>>>(inp, ids, wlut, blut, out, B);
  linmulti_v13<<<dim3(4, NMODELS), NT, 0, stream>>>(inp, ids, wlut, blut, out, B);
  linmulti_v13<<<dim3(4, NMODELS), NT, 0, stream>>>(inp, ids, wlut, blut, out, B);
}

// Round 4
// 89.477 us; speedup vs baseline: 1.2071x; 1.2071x over previous
//
#include <hip/hip_runtime.h>

#define NMODELS 128
#define SZ_IN 256
#define SZ_OUT 256
#define MAXLIST 192     // P(cnt>192) ~ 0 (clamped for safety)
#define NT 512          // 8 waves
#define FRAGSTRIDE 520  // shorts per fragment slot: 512 data + 8 stagger
#define CPB 64          // cols per block (quarter split)
#define NTILES 4        // 16-col n-tiles per block

typedef __attribute__((ext_vector_type(4))) float f32x4;
typedef __attribute__((ext_vector_type(8))) short bf16x8;

// fp32 -> bf16 RNE (bit pattern) — used on the one-shot W path
__device__ __forceinline__ short f2bf(float f) {
  union { float f; unsigned u; } v;
  v.f = f;
  const unsigned r = v.u + 0x7FFFu + ((v.u >> 16) & 1u);
  return (short)(r >> 16);
}

// HW packed cvt: 2 f32 -> u32 of 2 bf16 (RNE). No builtin on gfx950 (m240).
__device__ __forceinline__ unsigned pkbf(float lo, float hi) {
  unsigned r;
  asm("v_cvt_pk_bf16_f32 %0, %1, %2" : "=v"(r) : "v"(lo), "v"(hi));
  return r;
}

// R15: calibration (R14) showed K_warm ~= 11.7us vs ~6.3us HBM floor; fixed
// harness overhead ~72us dominates dur_us. This round: DELETE the A-LDS stage.
// A-fragments load directly from global (32 contiguous B per lane per kb),
// cvt via v_cvt_pk_bf16_f32. LDS 67.9 -> 34.1 KB => 3 blocks/CU
// (__launch_bounds__(512,6), VGPR cap 85). One less barrier; first-chunk A
// loads issued before the W scatter to hide latency under it.
// mfma_f32_16x16x32_bf16 layouts (HW-verified prior session):
//   A[mrow=lane&15][k=q*8+j], B[k=q*8+j][n=lane&15], D[row=q*4+r][col=lane&15]
__global__ __launch_bounds__(NT, 6) void linmulti_v15(
    const float* __restrict__ inp, const int* __restrict__ ids,
    const float* __restrict__ wlut, const float* __restrict__ blut,
    float* __restrict__ out, int B) {
  const int ch = blockIdx.x;   // 0..3 (64-col quarter)
  const int m = blockIdx.y;    // 0..127
  const int tid = threadIdx.x;
  const int lane = tid & 63;
  const int wv = tid >> 6;     // 0..7
  const int nt = wv & 3;       // n-tile (16 cols)
  const int par = wv >> 2;     // chunk parity: waves nt and nt+4 share B-frags
  const int q = lane >> 4;
  const int n16 = lane & 15;
  const int col = ch * CPB + nt * 16 + n16;

  __shared__ short Wfrag[32 * FRAGSTRIDE];  // 33,280 B: 8 kb x 4 ntiles
  __shared__ int list[MAXLIST];
  __shared__ int cnt0;

  if (tid == 0) cnt0 = 0;

  // ---- ids loads first (8 coalesced dwords/lane) ----
  int myid[8];
#pragma unroll
  for (int v = 0; v < 8; ++v) {
    const int b = v * NT + tid;
    myid[v] = (b < B) ? ids[b] : -1;
  }

  // ---- W slice, coalesced: 8 f32x4/thread, 256 B row segments ----
  const float* __restrict__ Wb = wlut + (size_t)m * (SZ_IN * SZ_OUT) + ch * CPB;
  f32x4 wraw[8];
#pragma unroll
  for (int v = 0; v < 8; ++v) {
    const int e4 = v * NT + tid;       // [0, 4096)
    const int r = e4 >> 4;             // k-row 0..255
    const int c4 = e4 & 15;            // f32x4 within the 64-col row
    wraw[v] = *(const f32x4*)(Wb + (size_t)r * SZ_OUT + c4 * 4);
  }

  __syncthreads();  // cnt0 = 0 visible

  // ---- member list: order-free atomic append (out rows are independent) ----
#pragma unroll
  for (int v = 0; v < 8; ++v) {
    if (myid[v] == m) {
      const int p = atomicAdd(&cnt0, 1);
      if (p < MAXLIST) list[p] = v * NT + tid;
    }
  }
  __syncthreads();
  const int cnt = (cnt0 < MAXLIST) ? cnt0 : MAXLIST;
  if (cnt == 0) return;  // uniform exit

  // ---- preload first A quarter (kb 0,1) of this wave's first chunk:
  //      latency hides under the W scatter below. 4 f32x4 = 16 VGPR.
  int prow = par * 16 + n16;
  if (prow > cnt - 1) prow = cnt - 1;
  const float* __restrict__ ap0 = inp + (size_t)list[prow] * SZ_IN;
  f32x4 apre[4];
#pragma unroll
  for (int j = 0; j < 4; ++j)
    apre[j] = ((const f32x4*)ap0)[(j >> 1) * 8 + q * 2 + (j & 1)];

  // ---- cvt + scatter W into fragment-ordered LDS ----
  // element (k-row r, col c) -> frag f = (r>>5)*NTILES + (c>>4),
  //   slot = ((r>>3 & 3)*16 + (c&15))*8 + (r&7)
#pragma unroll
  for (int v = 0; v < 8; ++v) {
    const int e4 = v * NT + tid;
    const int r = e4 >> 4;
    const int c0 = (e4 & 15) * 4;
    const int kb = r >> 5;
    const int qq = (r >> 3) & 3;
    const int jj = r & 7;
#pragma unroll
    for (int e = 0; e < 4; ++e) {
      const int c = c0 + e;
      Wfrag[(kb * NTILES + (c >> 4)) * FRAGSTRIDE + ((qq * 16) + (c & 15)) * 8 + jj] =
          f2bf(wraw[v][e]);
    }
  }
  __syncthreads();

  // ---- extract this wave's 8 B-fragments (linear ds_read_b128) ----
  bf16x8 bfr[8];
#pragma unroll
  for (int kb = 0; kb < 8; ++kb)
    bfr[kb] = *(const bf16x8*)(Wfrag + (kb * NTILES + nt) * FRAGSTRIDE + lane * 8);

  const float bias_c = blut[m * SZ_OUT + col];
  const int nchunk = (cnt + 15) >> 4;

  // ---- chunk loop: A direct from global, quarter-batched (2 kb / 4 f32x4) ----
  for (int c = par, first = 1; c < nchunk; c += 2, first = 0) {
    int rr = c * 16 + n16;
    if (rr > cnt - 1) rr = cnt - 1;  // pad rows clamp; stores guarded
    const float* __restrict__ ap = inp + (size_t)list[rr] * SZ_IN;

    f32x4 acc = (f32x4){0.f, 0.f, 0.f, 0.f};
#pragma unroll
    for (int h = 0; h < 4; ++h) {  // kb pair {2h, 2h+1}
      f32x4 ar[4];
      if (h == 0 && first) {
#pragma unroll
        for (int j = 0; j < 4; ++j) ar[j] = apre[j];
      } else {
#pragma unroll
        for (int j = 0; j < 4; ++j)
          ar[j] = ((const f32x4*)ap)[h * 16 + (j >> 1) * 8 + q * 2 + (j & 1)];
      }
#pragma unroll
      for (int kk = 0; kk < 2; ++kk) {  // kb = 2h + kk
        union { bf16x8 v; unsigned u[4]; } afr;
        afr.u[0] = pkbf(ar[2 * kk][0], ar[2 * kk][1]);
        afr.u[1] = pkbf(ar[2 * kk][2], ar[2 * kk][3]);
        afr.u[2] = pkbf(ar[2 * kk + 1][0], ar[2 * kk + 1][1]);
        afr.u[3] = pkbf(ar[2 * kk + 1][2], ar[2 * kk + 1][3]);
        acc = __builtin_amdgcn_mfma_f32_16x16x32_bf16(afr.v, bfr[h * 2 + kk], acc, 0, 0, 0);
      }
    }

#pragma unroll
    for (int r = 0; r < 4; ++r) {
      const int gr = c * 16 + q * 4 + r;
      if (gr < cnt)
        out[(size_t)list[gr] * SZ_OUT + col] = acc[r] + bias_c;
    }
  }
}

extern "C" void kernel_launch(void* const* d_in, const int* in_sizes, int n_in,
                              void* d_out, int out_size, void* d_ws, size_t ws_size,
                              hipStream_t stream) {
  const float* inp = (const float*)d_in[0];
  const int* ids = (const int*)d_in[1];
  const float* wlut = (const float*)d_in[2];
  const float* blut = (const float*)d_in[3];
  float* out = (float*)d_out;
  const int B = in_sizes[1];

  linmulti_v15<<<dim3(4, NMODELS), NT, 0, stream>>>(inp, ids, wlut, blut, out, B);
}

// Round 5
// 83.535 us; speedup vs baseline: 1.2930x; 1.0711x over previous
//
#include <hip/hip_runtime.h>

#define NMODELS 128
#define SZ_IN 256
#define SZ_OUT 256
#define MAXLIST 192     // P(cnt>192) ~ 0 (clamped for safety)
#define LDSK 264        // bf16 A-row stride: 2-way bank alias (free)
#define NT 512          // 8 waves
#define FRAGSTRIDE 520  // shorts per fragment slot: 512 data + 8 stagger
#define CPB 64          // cols per block (quarter split)
#define NTILES 4        // 16-col n-tiles per block
#define AROWS 64        // A rows staged per pass (covers max per-model cnt)

typedef __attribute__((ext_vector_type(4))) float f32x4;
typedef __attribute__((ext_vector_type(8))) short bf16x8;
typedef __attribute__((ext_vector_type(2))) unsigned u32x2;
typedef __attribute__((ext_vector_type(4))) unsigned u32x4;

// HW packed cvt: 2 f32 -> u32 of 2 bf16 (RNE, src0 in low half). No builtin
// on gfx950; inline asm per guide (T12/m240).
__device__ __forceinline__ unsigned pkbf(float lo, float hi) {
  unsigned r;
  asm("v_cvt_pk_bf16_f32 %0, %1, %2" : "=v"(r) : "v"(lo), "v"(hi));
  return r;
}

// R16 = R13 structure (best, 84.7us; R15's occupancy push spilled & regressed)
// + W-scatter rework: thread owns 8 k-rows x 4 cols -> per col 4x pkbf + ONE
// ds_write_b128 (uniform 2-way banks = free) instead of 32 scattered
// ds_write_b16 + ~96 VALU of bit-twiddle cvt. A-stage cvt also pkbf.
// Extract + MFMA fragment layouts byte-identical to R13 (HW-verified):
//   A[mrow=lane&15][k=q*8+j], B[k=q*8+j][n=lane&15], D[row=q*4+r][col=lane&15]
__global__ __launch_bounds__(NT, 4) void linmulti_v16(
    const float* __restrict__ inp, const int* __restrict__ ids,
    const float* __restrict__ wlut, const float* __restrict__ blut,
    float* __restrict__ out, int B) {
  const int ch = blockIdx.x;   // 0..3 (64-col quarter)
  const int m = blockIdx.y;    // 0..127
  const int tid = threadIdx.x;
  const int lane = tid & 63;
  const int wv = tid >> 6;     // 0..7
  const int nt = wv & 3;       // n-tile (16 cols)
  const int par = wv >> 2;     // chunk parity: waves nt and nt+4 share B-frags
  const int q = lane >> 4;
  const int n16 = lane & 15;
  const int col = ch * CPB + nt * 16 + n16;

  __shared__ short Wfrag[32 * FRAGSTRIDE];  // 33,280 B: 8 kb x 4 ntiles
  __shared__ short As[AROWS * LDSK];        // 33,792 B: staged A rows
  __shared__ int list[MAXLIST];
  __shared__ int cnt0;

  if (tid == 0) cnt0 = 0;

  // ---- ids loads first (8 coalesced dwords/lane) ----
  int myid[8];
#pragma unroll
  for (int v = 0; v < 8; ++v) {
    const int b = v * NT + tid;
    myid[v] = (b < B) ? ids[b] : -1;
  }

  // ---- W slice: thread owns rows rw*8..rw*8+7, cols c4*4..c4*4+3 ----
  // Per load v: 16-lane groups read 256 B contiguous (same coalescing as R13).
  const int rw = tid >> 4;   // 0..31: 8-row group
  const int c4 = tid & 15;   // f32x4 col group within the 64-col quarter
  const float* __restrict__ Wb = wlut + (size_t)m * (SZ_IN * SZ_OUT) + ch * CPB;
  f32x4 wraw[8];
#pragma unroll
  for (int v = 0; v < 8; ++v)
    wraw[v] = *(const f32x4*)(Wb + (size_t)(rw * 8 + v) * SZ_OUT + c4 * 4);

  __syncthreads();  // cnt0 = 0 visible

  // ---- member list: order-free atomic append (out rows are independent) ----
#pragma unroll
  for (int v = 0; v < 8; ++v) {
    if (myid[v] == m) {
      const int p = atomicAdd(&cnt0, 1);
      if (p < MAXLIST) list[p] = v * NT + tid;
    }
  }
  __syncthreads();
  const int cnt = (cnt0 < MAXLIST) ? cnt0 : MAXLIST;
  if (cnt == 0) return;  // uniform exit

  // ---- issue A-stage loads EARLY: latency hides under W scatter ----
  f32x4 araw[8];
#pragma unroll
  for (int v = 0; v < 8; ++v) {
    const int e4 = v * NT + tid;       // [0, 4096)
    const int s = e4 >> 6;             // staged row 0..63
    const int f4 = e4 & 63;            // f32x4 within 256-float row
    int p = s;
    if (p > cnt - 1) p = cnt - 1;      // pad rows clamp; stores guarded
    araw[v] = ((const f32x4*)(inp + (size_t)list[p] * SZ_IN))[f4];
  }

  // ---- W cvt + scatter: per col, 4 pkbf + one ds_write_b128 ----
  // k = rw*8 + v  ->  kb = rw>>2, qq = rw&3, jj = v (constant per thread).
  // dst slot shorts [((qq*16)+(c&15))*8 + 0..7] = k-rows 0..7 of col c.
  {
    const int kb = rw >> 2;
    const int qq = rw & 3;
#pragma unroll
    for (int e = 0; e < 4; ++e) {
      const int c = c4 * 4 + e;
      u32x4 pk;
      pk[0] = pkbf(wraw[0][e], wraw[1][e]);
      pk[1] = pkbf(wraw[2][e], wraw[3][e]);
      pk[2] = pkbf(wraw[4][e], wraw[5][e]);
      pk[3] = pkbf(wraw[6][e], wraw[7][e]);
      *(u32x4*)(Wfrag + (kb * NTILES + (c >> 4)) * FRAGSTRIDE +
                ((qq * 16) + (c & 15)) * 8) = pk;
    }
  }
  __syncthreads();

  // ---- extract this wave's 8 B-fragments (linear ds_read_b128) ----
  bf16x8 bfr[8];
#pragma unroll
  for (int kb = 0; kb < 8; ++kb)
    bfr[kb] = *(const bf16x8*)(Wfrag + (kb * NTILES + nt) * FRAGSTRIDE + lane * 8);

  const float bias_c = blut[m * SZ_OUT + col];

  // ---- pass loop (single pass for cnt <= 64; multi-pass for safety) ----
  for (int base = 0;;) {
    // write staged A (b64, conflict-free), pkbf cvt
#pragma unroll
    for (int v = 0; v < 8; ++v) {
      const int e4 = v * NT + tid;
      const int s = e4 >> 6;
      const int f4 = e4 & 63;
      u32x2 h;
      h[0] = pkbf(araw[v][0], araw[v][1]);
      h[1] = pkbf(araw[v][2], araw[v][3]);
      *(u32x2*)(As + s * LDSK + f4 * 4) = h;
    }
    __syncthreads();

    const int rows = ((cnt - base) < AROWS) ? (cnt - base) : AROWS;
    const int nchunk = (rows + 15) >> 4;
    // barrier-free compute: parity wave-sets split chunks
    for (int c = par; c < nchunk; c += 2) {
      f32x4 acc = (f32x4){0.f, 0.f, 0.f, 0.f};
#pragma unroll
      for (int kb = 0; kb < 8; ++kb) {
        const bf16x8 afr =
            *(const bf16x8*)(As + (c * 16 + n16) * LDSK + kb * 32 + q * 8);
        acc = __builtin_amdgcn_mfma_f32_16x16x32_bf16(afr, bfr[kb], acc, 0, 0, 0);
      }
#pragma unroll
      for (int r = 0; r < 4; ++r) {
        const int gr = base + c * 16 + q * 4 + r;
        if (gr < cnt)
          out[(size_t)list[gr] * SZ_OUT + col] = acc[r] + bias_c;
      }
    }

    base += AROWS;
    if (base >= cnt) break;
    __syncthreads();  // readers done before re-staging As (rare path)
#pragma unroll
    for (int v = 0; v < 8; ++v) {
      const int e4 = v * NT + tid;
      const int s = e4 >> 6;
      const int f4 = e4 & 63;
      int p = base + s;
      if (p > cnt - 1) p = cnt - 1;
      araw[v] = ((const f32x4*)(inp + (size_t)list[p] * SZ_IN))[f4];
    }
  }
}

extern "C" void kernel_launch(void* const* d_in, const int* in_sizes, int n_in,
                              void* d_out, int out_size, void* d_ws, size_t ws_size,
                              hipStream_t stream) {
  const float* inp = (const float*)d_in[0];
  const int* ids = (const int*)d_in[1];
  const float* wlut = (const float*)d_in[2];
  const float* blut = (const float*)d_in[3];
  float* out = (float*)d_out;
  const int B = in_sizes[1];

  linmulti_v16<<<dim3(4, NMODELS), NT, 0, stream>>>(inp, ids, wlut, blut, out, B);
}